// Round 14
// baseline (132.564 us; speedup 1.0000x reference)
//
#include <hip/hip_runtime.h>

#define B_ 4
#define S_ 512
#define T_ 512
#define D_ 256
#define NSRC (B_ * S_)            // 2048 source rows
#define NROW 4096                 // src rows + tgt rows
#define K2F 2.8853900817779268f   // 2*log2(e): exp2(x*K2F) = e^(2x)

typedef __attribute__((ext_vector_type(8))) short short8;      // 8 bf16
typedef __attribute__((ext_vector_type(8))) _Float16 half8;    // 8 f16
typedef __attribute__((ext_vector_type(4))) float f32x4;
typedef __attribute__((ext_vector_type(2))) float f32x2;

__device__ __forceinline__ unsigned short f2bf(float f) {
    union { float f; unsigned u; } v; v.f = f;
    unsigned r = v.u + 0x7FFF + ((v.u >> 16) & 1);   // RNE
    return (unsigned short)(r >> 16);
}

// ---------------------------------------------------------------------------
// K1: ysyt+prob (VERBATIM R12/R13, proven). 768 blocks x 256 thr.
// ---------------------------------------------------------------------------
__global__ __launch_bounds__(256) void ysyt_kernel(
    const float* __restrict__ src, const float* __restrict__ tgt,
    const float* __restrict__ Wsrc, const float* __restrict__ Wtgt,
    const float* __restrict__ Wp,  const float* __restrict__ bp,
    const float* __restrict__ bsrc, const float* __restrict__ btgt,
    _Float16* __restrict__ ytr, float* __restrict__ out)
{
    __shared__ unsigned short lwt[16384];    // 32 KB
    __shared__ _Float16 ltb[64][72];         // 9.2 KB bounce tile
    const int bid = blockIdx.x, tid = threadIdx.x;
    const int lane = tid & 63, w = tid >> 6;

    if (bid < 256) {
        const int rowblk = bid >> 2, colq = bid & 3;
        const int R0 = rowblk * 64;
        const int n = lane & 15, quad = lane >> 4;
        const int mat = (R0 >= NSRC) ? 1 : 0;
        const float* bias = mat ? btgt : bsrc;
        const float* Wm = mat ? Wtgt : Wsrc;
        const float* xb = mat ? &tgt[(R0 - NSRC) * D_] : &src[R0 * D_];

        {   // W-slab transpose -> lwt
            const int r = tid;
            const int ksr = r >> 5, qr = (r >> 3) & 3, jr = r & 7;
            const int wbase = ksr * 512 + qr * 8 + jr;
            #pragma unroll 4
            for (int i = 0; i < 16; i++) {
                float4 v = *(const float4*)&Wm[r * D_ + colq * 64 + 4 * i];
                const int cc = 4 * i;
                lwt[((cc + 0) >> 4) * 4096 + ((cc + 0) & 15) * 32 + wbase] = f2bf(v.x);
                lwt[((cc + 1) >> 4) * 4096 + ((cc + 1) & 15) * 32 + wbase] = f2bf(v.y);
                lwt[((cc + 2) >> 4) * 4096 + ((cc + 2) & 15) * 32 + wbase] = f2bf(v.z);
                lwt[((cc + 3) >> 4) * 4096 + ((cc + 3) & 15) * 32 + wbase] = f2bf(v.w);
            }
        }

        short8 af[8];
        #pragma unroll
        for (int ks = 0; ks < 8; ks++) {
            const float* p = &xb[(w * 16 + n) * D_ + ks * 32 + quad * 8];
            float4 u0 = *(const float4*)p;
            float4 u1 = *(const float4*)(p + 4);
            short8 v;
            v[0] = (short)f2bf(u0.x); v[1] = (short)f2bf(u0.y);
            v[2] = (short)f2bf(u0.z); v[3] = (short)f2bf(u0.w);
            v[4] = (short)f2bf(u1.x); v[5] = (short)f2bf(u1.y);
            v[6] = (short)f2bf(u1.z); v[7] = (short)f2bf(u1.w);
            af[ks] = v;
        }
        __syncthreads();

        #pragma unroll
        for (int gc = 0; gc < 4; gc++) {
            const int gcol = colq * 4 + gc;
            const unsigned short* bp2 = &lwt[gc * 4096 + n * 32 + quad * 8];
            short8 bf[8];
            #pragma unroll
            for (int ks = 0; ks < 8; ks++) bf[ks] = *(const short8*)&bp2[ks * 512];
            f32x4 a4 = {0.f, 0.f, 0.f, 0.f};
            #pragma unroll
            for (int ks = 0; ks < 8; ks++)
                a4 = __builtin_amdgcn_mfma_f32_16x16x32_bf16(af[ks], bf[ks], a4, 0, 0, 0);
            const float bv = bias[gcol * 16 + n];
            const int rl = w * 16 + quad * 4;
            const int dl = gc * 16 + n;
            ltb[rl + 0][dl] = (_Float16)fminf(__builtin_amdgcn_exp2f((a4[0] + bv) * K2F), 60000.f);
            ltb[rl + 1][dl] = (_Float16)fminf(__builtin_amdgcn_exp2f((a4[1] + bv) * K2F), 60000.f);
            ltb[rl + 2][dl] = (_Float16)fminf(__builtin_amdgcn_exp2f((a4[2] + bv) * K2F), 60000.f);
            ltb[rl + 3][dl] = (_Float16)fminf(__builtin_amdgcn_exp2f((a4[3] + bv) * K2F), 60000.f);
        }
        __syncthreads();
        {
            const int row = tid >> 2, seg = tid & 3;
            half8 v0 = *(const half8*)&ltb[row][seg * 16];
            half8 v1 = *(const half8*)&ltb[row][seg * 16 + 8];
            _Float16* dst = &ytr[(size_t)(R0 + row) * D_ + colq * 64 + seg * 16];
            *(half8*)&dst[0] = v0;
            *(half8*)&dst[8] = v1;
        }
    } else {
        int row  = (bid - 256) * 4 + w;
        float p0 = 0.f, p1 = 0.f;
        #pragma unroll
        for (int i = 0; i < 4; i++) {
            int d = lane + i * 64;
            float v = tgt[row * D_ + d];
            float2 wv = *(const float2*)&Wp[d * 2];
            p0 = fmaf(v, wv.x, p0);
            p1 = fmaf(v, wv.y, p1);
        }
        #pragma unroll
        for (int off = 32; off > 0; off >>= 1) {
            p0 += __shfl_down(p0, off, 64);
            p1 += __shfl_down(p1, off, 64);
        }
        if (lane == 0) {
            const float L2E = 1.4426950408889634f;
            float l0 = p0 + bp[0], l1 = p1 + bp[1];
            float e10 = __builtin_amdgcn_exp2f((l1 - l0) * L2E);
            float e01 = __builtin_amdgcn_exp2f((l0 - l1) * L2E);
            out[B_ * T_ * S_ + row * 2 + 0] = __builtin_amdgcn_rcpf(1.f + e10);
            out[B_ * T_ * S_ + row * 2 + 1] = __builtin_amdgcn_rcpf(1.f + e01);
        }
    }
}

// ---------------------------------------------------------------------------
// K2: genp v10 — INSTRUMENTATION BUILD (v9 + 2 changes):
//  (1) compute loop repeated 2x so the dispatch (~60us) displaces a ~41us
//      fill in rocprof top-5 -> first-ever counters for the real genp loop.
//      acc accumulates 2*Sum (both reps feed acc -> no DCE); store C0 - acc
//      (exact: C0 - 2*Sum). Remove the rep loop next round once read.
//  (2) Wres moved OUT of the inner loop into LDS (lw, 1KB, staged once,
//      read via 2 broadcast ds_read_b128/kq). v9 read Wres via in-loop
//      s_load; SMEM+DS share lgkmcnt but return cross-queue UNORDERED ->
//      compiler must emit lgkmcnt(0) full drains per iteration. If that
//      drain is the 3x dilation, VALUBusy jumps to ~55-65% here.
// Everything else verbatim v9 (passed, absmax 0.0078): 32s x 32t, f16
// full-D single-barrier tile, 4 blk/CU, plain stores.
// ---------------------------------------------------------------------------
__global__ __launch_bounds__(256) void genp_kernel(
    const _Float16* __restrict__ ytr,   // [4096][256]
    const float* __restrict__ Wres, const float* __restrict__ bres,
    float* __restrict__ out)
{
    __shared__ _Float16 lys[32][264];   // 16.9 KB
    __shared__ _Float16 lyt[32][264];   // 16.9 KB
    __shared__ float lw[256];           // 1 KB: Wres (no SMEM in loop)

    const int tid = threadIdx.x;
    const int lane = tid & 63;
    const int s0 = blockIdx.x * 32;
    const int t0 = blockIdx.y * 32;
    const int b  = blockIdx.z;
    const int m  = tid & 15;             // s rows m, m+16
    const int g  = tid >> 4;             // t rows g, g+16  (0..15)

    // ---- stage ALL 256 d + Wres in one burst ----
    {
        const int srow = tid >> 3;       // 0..31
        const int seg  = tid & 7;        // 0..7, 32 halves each
        const size_t gs = (size_t)(b * S_ + s0 + srow) * D_ + seg * 32;
        const size_t gt = (size_t)(NSRC + b * T_ + t0 + srow) * D_ + seg * 32;
        #pragma unroll
        for (int j = 0; j < 4; j++) {
            *(half8*)&lys[srow][seg * 32 + 8 * j] = *(const half8*)&ytr[gs + 8 * j];
            *(half8*)&lyt[srow][seg * 32 + 8 * j] = *(const half8*)&ytr[gt + 8 * j];
        }
        if (tid < 64) *(float4*)&lw[4 * tid] = *(const float4*)&Wres[4 * tid];
    }
    __syncthreads();                     // the ONLY barrier

    f32x2 acc[2];                        // [t-row i]; lanes = (s=m, s=m+16)
    acc[0] = (f32x2){0.f, 0.f};
    acc[1] = (f32x2){0.f, 0.f};
    const f32x2 one2 = {1.f, 1.f};

    for (int rep = 0; rep < 2; rep++) {  // INSTRUMENTATION: 2x (acc -> 2*Sum)
        #pragma unroll 4
        for (int kq = 0; kq < 32; kq++) {
            half8 sL = *(const half8*)&lys[m][8 * kq];
            half8 sH = *(const half8*)&lys[m + 16][8 * kq];
            half8 tL = *(const half8*)&lyt[g][8 * kq];
            half8 tH = *(const half8*)&lyt[g + 16][8 * kq];
            float4 wA = *(const float4*)&lw[8 * kq];       // broadcast ds_read
            float4 wB = *(const float4*)&lw[8 * kq + 4];
            f32x2 sp[8];
            float tLf[8], tHf[8];
            f32x2 wv[8];
            #pragma unroll
            for (int k = 0; k < 8; k++) {
                sp[k] = (f32x2){(float)sL[k], (float)sH[k]};
                tLf[k] = (float)tL[k];
                tHf[k] = (float)tH[k];
            }
            wv[0] = (f32x2){wA.x, wA.x}; wv[1] = (f32x2){wA.y, wA.y};
            wv[2] = (f32x2){wA.z, wA.z}; wv[3] = (f32x2){wA.w, wA.w};
            wv[4] = (f32x2){wB.x, wB.x}; wv[5] = (f32x2){wB.y, wB.y};
            wv[6] = (f32x2){wB.z, wB.z}; wv[7] = (f32x2){wB.w, wB.w};
            // 8-term rcp fold (proven math), once per t-row
            #define FOLD(TT, TF) {                                            \
                f32x2 dd[8];                                                  \
                _Pragma("unroll")                                             \
                for (int k = 0; k < 8; k++) {                                 \
                    const f32x2 cs2 = {TF[k], TF[k]};                         \
                    dd[k] = sp[k] * cs2 + one2;                               \
                }                                                             \
                f32x2 p01 = dd[0] * dd[1];                                    \
                f32x2 p23 = dd[2] * dd[3];                                    \
                f32x2 p45 = dd[4] * dd[5];                                    \
                f32x2 p67 = dd[6] * dd[7];                                    \
                f32x2 q03 = p01 * p23;                                        \
                f32x2 q47 = p45 * p67;                                        \
                f32x2 den = q03 * q47;                                        \
                f32x2 u01 = dd[1] * wv[0]; u01 = dd[0] * wv[1] + u01;         \
                f32x2 u23 = dd[3] * wv[2]; u23 = dd[2] * wv[3] + u23;         \
                f32x2 u45 = dd[5] * wv[4]; u45 = dd[4] * wv[5] + u45;         \
                f32x2 u67 = dd[7] * wv[6]; u67 = dd[6] * wv[7] + u67;         \
                f32x2 n03 = u01 * p23; n03 = u23 * p01 + n03;                 \
                f32x2 n47 = u45 * p67; n47 = u67 * p45 + n47;                 \
                f32x2 num = n03 * q47; num = n47 * q03 + num;                 \
                f32x2 rr;                                                     \
                rr.x = __builtin_amdgcn_rcpf(den.x);                          \
                rr.y = __builtin_amdgcn_rcpf(den.y);                          \
                acc[TT] = num * rr + acc[TT];                                 \
            }
            FOLD(0, tLf) FOLD(1, tHf)
            #undef FOLD
        }
    }

    // C0 per-wave butterfly; acc holds 2*Sum -> out = C0 - acc
    float cw = Wres[lane] + Wres[lane + 64] + Wres[lane + 128] + Wres[lane + 192];
    #pragma unroll
    for (int off = 32; off > 0; off >>= 1) cw += __shfl_xor(cw, off, 64);
    const float C0 = cw + bres[0];

    out[(size_t)(b * T_ + t0 + g     ) * S_ + s0 + m     ] = C0 - acc[0].x;
    out[(size_t)(b * T_ + t0 + g     ) * S_ + s0 + m + 16] = C0 - acc[0].y;
    out[(size_t)(b * T_ + t0 + g + 16) * S_ + s0 + m     ] = C0 - acc[1].x;
    out[(size_t)(b * T_ + t0 + g + 16) * S_ + s0 + m + 16] = C0 - acc[1].y;
}

extern "C" void kernel_launch(void* const* d_in, const int* in_sizes, int n_in,
                              void* d_out, int out_size, void* d_ws, size_t ws_size,
                              hipStream_t stream) {
    const float* source = (const float*)d_in[0];
    const float* target = (const float*)d_in[1];
    const float* W_src  = (const float*)d_in[2];
    const float* b_src  = (const float*)d_in[3];
    const float* W_tgt  = (const float*)d_in[4];
    const float* b_tgt  = (const float*)d_in[5];
    const float* W_res  = (const float*)d_in[6];
    const float* b_res  = (const float*)d_in[7];
    const float* W_prob = (const float*)d_in[8];
    const float* b_prob = (const float*)d_in[9];
    float* out = (float*)d_out;

    _Float16* ytr = (_Float16*)d_ws;           // [4096][256] f16 = 2 MB

    ysyt_kernel<<<768, 256, 0, stream>>>(source, target, W_src, W_tgt,
                                         W_prob, b_prob, b_src, b_tgt,
                                         ytr, out);
    genp_kernel<<<dim3(16, 16, 4), 256, 0, stream>>>(ytr, W_res, b_res, out);
}

// Round 15
// 107.431 us; speedup vs baseline: 1.2339x; 1.2339x over previous
//
#include <hip/hip_runtime.h>

#define B_ 4
#define S_ 512
#define T_ 512
#define D_ 256
#define NSRC (B_ * S_)            // 2048 source rows
#define NROW 4096                 // src rows + tgt rows
#define K2F 2.8853900817779268f   // 2*log2(e): exp2(x*K2F) = e^(2x)

typedef __attribute__((ext_vector_type(8))) short short8;      // 8 bf16
typedef __attribute__((ext_vector_type(8))) _Float16 half8;    // 8 f16
typedef __attribute__((ext_vector_type(4))) float f32x4;
typedef __attribute__((ext_vector_type(2))) float f32x2;

__device__ __forceinline__ unsigned short f2bf(float f) {
    union { float f; unsigned u; } v; v.f = f;
    unsigned r = v.u + 0x7FFF + ((v.u >> 16) & 1);   // RNE
    return (unsigned short)(r >> 16);
}

// ---------------------------------------------------------------------------
// K1: ysyt+prob (VERBATIM R12/R13/R14, proven). 768 blocks x 256 thr.
// ---------------------------------------------------------------------------
__global__ __launch_bounds__(256) void ysyt_kernel(
    const float* __restrict__ src, const float* __restrict__ tgt,
    const float* __restrict__ Wsrc, const float* __restrict__ Wtgt,
    const float* __restrict__ Wp,  const float* __restrict__ bp,
    const float* __restrict__ bsrc, const float* __restrict__ btgt,
    _Float16* __restrict__ ytr, float* __restrict__ out)
{
    __shared__ unsigned short lwt[16384];    // 32 KB
    __shared__ _Float16 ltb[64][72];         // 9.2 KB bounce tile
    const int bid = blockIdx.x, tid = threadIdx.x;
    const int lane = tid & 63, w = tid >> 6;

    if (bid < 256) {
        const int rowblk = bid >> 2, colq = bid & 3;
        const int R0 = rowblk * 64;
        const int n = lane & 15, quad = lane >> 4;
        const int mat = (R0 >= NSRC) ? 1 : 0;
        const float* bias = mat ? btgt : bsrc;
        const float* Wm = mat ? Wtgt : Wsrc;
        const float* xb = mat ? &tgt[(R0 - NSRC) * D_] : &src[R0 * D_];

        {   // W-slab transpose -> lwt
            const int r = tid;
            const int ksr = r >> 5, qr = (r >> 3) & 3, jr = r & 7;
            const int wbase = ksr * 512 + qr * 8 + jr;
            #pragma unroll 4
            for (int i = 0; i < 16; i++) {
                float4 v = *(const float4*)&Wm[r * D_ + colq * 64 + 4 * i];
                const int cc = 4 * i;
                lwt[((cc + 0) >> 4) * 4096 + ((cc + 0) & 15) * 32 + wbase] = f2bf(v.x);
                lwt[((cc + 1) >> 4) * 4096 + ((cc + 1) & 15) * 32 + wbase] = f2bf(v.y);
                lwt[((cc + 2) >> 4) * 4096 + ((cc + 2) & 15) * 32 + wbase] = f2bf(v.z);
                lwt[((cc + 3) >> 4) * 4096 + ((cc + 3) & 15) * 32 + wbase] = f2bf(v.w);
            }
        }

        short8 af[8];
        #pragma unroll
        for (int ks = 0; ks < 8; ks++) {
            const float* p = &xb[(w * 16 + n) * D_ + ks * 32 + quad * 8];
            float4 u0 = *(const float4*)p;
            float4 u1 = *(const float4*)(p + 4);
            short8 v;
            v[0] = (short)f2bf(u0.x); v[1] = (short)f2bf(u0.y);
            v[2] = (short)f2bf(u0.z); v[3] = (short)f2bf(u0.w);
            v[4] = (short)f2bf(u1.x); v[5] = (short)f2bf(u1.y);
            v[6] = (short)f2bf(u1.z); v[7] = (short)f2bf(u1.w);
            af[ks] = v;
        }
        __syncthreads();

        #pragma unroll
        for (int gc = 0; gc < 4; gc++) {
            const int gcol = colq * 4 + gc;
            const unsigned short* bp2 = &lwt[gc * 4096 + n * 32 + quad * 8];
            short8 bf[8];
            #pragma unroll
            for (int ks = 0; ks < 8; ks++) bf[ks] = *(const short8*)&bp2[ks * 512];
            f32x4 a4 = {0.f, 0.f, 0.f, 0.f};
            #pragma unroll
            for (int ks = 0; ks < 8; ks++)
                a4 = __builtin_amdgcn_mfma_f32_16x16x32_bf16(af[ks], bf[ks], a4, 0, 0, 0);
            const float bv = bias[gcol * 16 + n];
            const int rl = w * 16 + quad * 4;
            const int dl = gc * 16 + n;
            ltb[rl + 0][dl] = (_Float16)fminf(__builtin_amdgcn_exp2f((a4[0] + bv) * K2F), 60000.f);
            ltb[rl + 1][dl] = (_Float16)fminf(__builtin_amdgcn_exp2f((a4[1] + bv) * K2F), 60000.f);
            ltb[rl + 2][dl] = (_Float16)fminf(__builtin_amdgcn_exp2f((a4[2] + bv) * K2F), 60000.f);
            ltb[rl + 3][dl] = (_Float16)fminf(__builtin_amdgcn_exp2f((a4[3] + bv) * K2F), 60000.f);
        }
        __syncthreads();
        {
            const int row = tid >> 2, seg = tid & 3;
            half8 v0 = *(const half8*)&ltb[row][seg * 16];
            half8 v1 = *(const half8*)&ltb[row][seg * 16 + 8];
            _Float16* dst = &ytr[(size_t)(R0 + row) * D_ + colq * 64 + seg * 16];
            *(half8*)&dst[0] = v0;
            *(half8*)&dst[8] = v1;
        }
    } else {
        int row  = (bid - 256) * 4 + w;
        float p0 = 0.f, p1 = 0.f;
        #pragma unroll
        for (int i = 0; i < 4; i++) {
            int d = lane + i * 64;
            float v = tgt[row * D_ + d];
            float2 wv = *(const float2*)&Wp[d * 2];
            p0 = fmaf(v, wv.x, p0);
            p1 = fmaf(v, wv.y, p1);
        }
        #pragma unroll
        for (int off = 32; off > 0; off >>= 1) {
            p0 += __shfl_down(p0, off, 64);
            p1 += __shfl_down(p1, off, 64);
        }
        if (lane == 0) {
            const float L2E = 1.4426950408889634f;
            float l0 = p0 + bp[0], l1 = p1 + bp[1];
            float e10 = __builtin_amdgcn_exp2f((l1 - l0) * L2E);
            float e01 = __builtin_amdgcn_exp2f((l0 - l1) * L2E);
            out[B_ * T_ * S_ + row * 2 + 0] = __builtin_amdgcn_rcpf(1.f + e10);
            out[B_ * T_ * S_ + row * 2 + 1] = __builtin_amdgcn_rcpf(1.f + e01);
        }
    }
}

// ---------------------------------------------------------------------------
// K2: genp v11 — VALU-count reduction via 4s x 2t thread tile.
// R14 counters (first genp readout): VALUBusy 69-72%, no spill, conflicts
// negligible -> genp is VALU-INSTRUCTION-bound (~203 inst/kq: fold fully
// scalarized 124 + cvt 32 + w/misc ~47). Lever = fewer inst/term:
//   v9/v10 (2s x 2t): 6.25 inst/term (cvt 1.0/term)
//   v11    (4s x 2t): ~4.8 inst/term (cvt 48/64 = 0.75, w amortized 2x)
// Tile 64s x 32t, full d, grid (8,16,4) = 512 blocks = 2 blk/CU
// (LDS 51.7 KB). Single barrier (v9), f16 row-major tile, stride 264
// (all reads <=2-way bank aliasing = free), Wres in LDS (v10), plain
// stores, rep loop REMOVED (back to out = C0 - 2*acc).
// genP = C0 - 2 * sum_d w_d / (1 + ys*yt),  C0 = sum w + b_res.
// ---------------------------------------------------------------------------
__global__ __launch_bounds__(256) void genp_kernel(
    const _Float16* __restrict__ ytr,   // [4096][256]
    const float* __restrict__ Wres, const float* __restrict__ bres,
    float* __restrict__ out)
{
    __shared__ _Float16 lys[64][264];   // 33.8 KB
    __shared__ _Float16 lyt[32][264];   // 16.9 KB
    __shared__ float lw[256];           // 1 KB

    const int tid = threadIdx.x;
    const int lane = tid & 63;
    const int s0 = blockIdx.x * 64;
    const int t0 = blockIdx.y * 32;
    const int b  = blockIdx.z;
    const int m  = tid & 15;             // s rows m, m+16, m+32, m+48
    const int g  = tid >> 4;             // t rows g, g+16  (g = 0..15)

    // ---- stage 96 rows x 256 d (48 KB) + Wres, one burst, one barrier ----
    // flat map: u = tid + 256*jj; row = u>>5 (0..95), c8 = u&31 (16B units).
    // jj 0..7 -> s rows 0..63; jj 8..11 -> t rows 0..31 (compile-time split).
    #pragma unroll
    for (int jj = 0; jj < 12; jj++) {
        const int u = tid + 256 * jj;
        const int row = u >> 5;
        const int c8  = u & 31;
        if (row < 64) {
            const size_t grow = (size_t)(b * S_ + s0 + row);
            *(half8*)&lys[row][8 * c8] = *(const half8*)&ytr[grow * D_ + 8 * c8];
        } else {
            const size_t grow = (size_t)(NSRC + b * T_ + t0 + (row - 64));
            *(half8*)&lyt[row - 64][8 * c8] = *(const half8*)&ytr[grow * D_ + 8 * c8];
        }
    }
    if (tid < 64) *(float4*)&lw[4 * tid] = *(const float4*)&Wres[4 * tid];
    __syncthreads();                     // the ONLY barrier

    f32x2 acc[2][2];                     // [t-row i][s-halfpair h]
    acc[0][0] = (f32x2){0.f, 0.f}; acc[0][1] = (f32x2){0.f, 0.f};
    acc[1][0] = (f32x2){0.f, 0.f}; acc[1][1] = (f32x2){0.f, 0.f};
    const f32x2 one2 = {1.f, 1.f};

    #pragma unroll 2
    for (int kq = 0; kq < 32; kq++) {
        half8 sv0 = *(const half8*)&lys[m     ][8 * kq];
        half8 sv1 = *(const half8*)&lys[m + 16][8 * kq];
        half8 sv2 = *(const half8*)&lys[m + 32][8 * kq];
        half8 sv3 = *(const half8*)&lys[m + 48][8 * kq];
        half8 tv0 = *(const half8*)&lyt[g     ][8 * kq];
        half8 tv1 = *(const half8*)&lyt[g + 16][8 * kq];
        float4 wA = *(const float4*)&lw[8 * kq];       // broadcast ds_read
        float4 wB = *(const float4*)&lw[8 * kq + 4];
        f32x2 spA[8], spB[8];
        float tLf[8], tHf[8];
        f32x2 wv[8];
        #pragma unroll
        for (int k = 0; k < 8; k++) {
            spA[k] = (f32x2){(float)sv0[k], (float)sv1[k]};
            spB[k] = (f32x2){(float)sv2[k], (float)sv3[k]};
            tLf[k] = (float)tv0[k];
            tHf[k] = (float)tv1[k];
        }
        wv[0] = (f32x2){wA.x, wA.x}; wv[1] = (f32x2){wA.y, wA.y};
        wv[2] = (f32x2){wA.z, wA.z}; wv[3] = (f32x2){wA.w, wA.w};
        wv[4] = (f32x2){wB.x, wB.x}; wv[5] = (f32x2){wB.y, wB.y};
        wv[6] = (f32x2){wB.z, wB.z}; wv[7] = (f32x2){wB.w, wB.w};

        // 8-term rcp fold (proven math): 4 instances = {tL,tH} x {spA,spB}
        #define FOLD(TI, HH, TF, SP) {                                        \
            f32x2 dd[8];                                                      \
            _Pragma("unroll")                                                 \
            for (int k = 0; k < 8; k++) {                                     \
                const f32x2 cs2 = {TF[k], TF[k]};                             \
                dd[k] = SP[k] * cs2 + one2;                                   \
            }                                                                 \
            f32x2 p01 = dd[0] * dd[1];                                        \
            f32x2 p23 = dd[2] * dd[3];                                        \
            f32x2 p45 = dd[4] * dd[5];                                        \
            f32x2 p67 = dd[6] * dd[7];                                        \
            f32x2 q03 = p01 * p23;                                            \
            f32x2 q47 = p45 * p67;                                            \
            f32x2 den = q03 * q47;                                            \
            f32x2 u01 = dd[1] * wv[0]; u01 = dd[0] * wv[1] + u01;             \
            f32x2 u23 = dd[3] * wv[2]; u23 = dd[2] * wv[3] + u23;             \
            f32x2 u45 = dd[5] * wv[4]; u45 = dd[4] * wv[5] + u45;             \
            f32x2 u67 = dd[7] * wv[6]; u67 = dd[6] * wv[7] + u67;             \
            f32x2 n03 = u01 * p23; n03 = u23 * p01 + n03;                     \
            f32x2 n47 = u45 * p67; n47 = u67 * p45 + n47;                     \
            f32x2 num = n03 * q47; num = n47 * q03 + num;                     \
            f32x2 rr;                                                         \
            rr.x = __builtin_amdgcn_rcpf(den.x);                              \
            rr.y = __builtin_amdgcn_rcpf(den.y);                              \
            acc[TI][HH] = num * rr + acc[TI][HH];                             \
        }
        FOLD(0, 0, tLf, spA) FOLD(0, 1, tLf, spB)
        FOLD(1, 0, tHf, spA) FOLD(1, 1, tHf, spB)
        #undef FOLD
    }

    // C0 per-wave butterfly; plain stores
    float cw = Wres[lane] + Wres[lane + 64] + Wres[lane + 128] + Wres[lane + 192];
    #pragma unroll
    for (int off = 32; off > 0; off >>= 1) cw += __shfl_xor(cw, off, 64);
    const float C0 = cw + bres[0];

    #pragma unroll
    for (int i = 0; i < 2; i++) {
        float* orow = &out[(size_t)(b * T_ + t0 + g + 16 * i) * S_ + s0];
        orow[m     ] = C0 - 2.f * acc[i][0].x;
        orow[m + 16] = C0 - 2.f * acc[i][0].y;
        orow[m + 32] = C0 - 2.f * acc[i][1].x;
        orow[m + 48] = C0 - 2.f * acc[i][1].y;
    }
}

extern "C" void kernel_launch(void* const* d_in, const int* in_sizes, int n_in,
                              void* d_out, int out_size, void* d_ws, size_t ws_size,
                              hipStream_t stream) {
    const float* source = (const float*)d_in[0];
    const float* target = (const float*)d_in[1];
    const float* W_src  = (const float*)d_in[2];
    const float* b_src  = (const float*)d_in[3];
    const float* W_tgt  = (const float*)d_in[4];
    const float* b_tgt  = (const float*)d_in[5];
    const float* W_res  = (const float*)d_in[6];
    const float* b_res  = (const float*)d_in[7];
    const float* W_prob = (const float*)d_in[8];
    const float* b_prob = (const float*)d_in[9];
    float* out = (float*)d_out;

    _Float16* ytr = (_Float16*)d_ws;           // [4096][256] f16 = 2 MB

    ysyt_kernel<<<768, 256, 0, stream>>>(source, target, W_src, W_tgt,
                                         W_prob, b_prob, b_src, b_tgt,
                                         ytr, out);
    genp_kernel<<<dim3(8, 16, 4), 256, 0, stream>>>(ytr, W_res, b_res, out);
}